// Round 14
// baseline (119.157 us; speedup 1.0000x reference)
//
#include <hip/hip_runtime.h>

#define RES    256
#define NPIX   (RES * RES)
#define NTRI   1000
#define EPSF   1e-8f
#define CPT    12            // coef dwords per triangle
#define CAPC   320           // staged records per LDS pass
#define LOG2E2 2.8853900817779268f   // 2*log2(e)

// coef (12 f32/tri): a0,b0,c0,a1,b1,c1,a2,b2,c2, ik, mn*ik, pad
//   edge_i(px,py)=a*px+b*py+c ; x2=fma(s,ik,-mn*ik) ; tanh = 1 - 2*rcp(1+exp2(x2))
// bbox (1 u32/tri): bx0 | bx1<<8 | by0<<16 | by1<<24 ; empty = 0x00FF00FF
//
// tri_setup math (no grid scan):
//  mn = min over the 4 grid corners (s quasi-concave: any outside px implies an
//  outside corner with s=0 exactly; fully-inside grid -> lattice min at corner).
//  mx = max over rows of the row max; per row s(x) is log-concave, integer max
//  adjacent to a root of d/dx log s = 0 (quadratic). Candidates evaluated with
//  the SAME fmaf tree rasterize uses (exact cancellation at the min).

// ---------------------------------------------------------------------------
// Kernel A: one block per (batch, triangle). Thread = one bbox row.
// ---------------------------------------------------------------------------
__global__ __launch_bounds__(256) void tri_setup(
    const float* __restrict__ meshes, const float* __restrict__ Km,
    const int* __restrict__ midx, const float* __restrict__ cams,
    float* __restrict__ coef, unsigned int* __restrict__ bbox)
{
    const int blk = blockIdx.x;
    const int b = blk / NTRI;
    const int t = blk - b * NTRI;

    const float* cam = cams + b * 12;
    float M[12];
#pragma unroll
    for (int i = 0; i < 3; ++i) {
        const float k0 = Km[i*3+0], k1 = Km[i*3+1], k2 = Km[i*3+2];
#pragma unroll
        for (int j = 0; j < 4; ++j)
            M[i*4+j] = k0*cam[j] + k1*cam[4+j] + k2*cam[8+j];
    }
    const int m = midx[b];
    const float* tv = meshes + ((size_t)m * NTRI + t) * 9;
    float vx[3], vy[3];
#pragma unroll
    for (int v = 0; v < 3; ++v) {
        const float X = tv[v*3+0], Y = tv[v*3+1], Z = tv[v*3+2];
        const float w = M[8]*X + M[9]*Y + M[10]*Z + M[11] + EPSF;
        vx[v] = (M[0]*X + M[1]*Y + M[2]*Z + M[3]) / w;
        vy[v] = (M[4]*X + M[5]*Y + M[6]*Z + M[7]) / w;
    }

    const float e0x = vx[1]-vx[0], e0y = vy[1]-vy[0];
    const float e1x = vx[2]-vx[1], e1y = vy[2]-vy[1];
    const float e2x = vx[0]-vx[2], e2y = vy[0]-vy[2];
    const float N = e0x*e2y - e0y*e2x + EPSF;

    const float a0 = N*e0y, b0 = -N*e0x, c0 = N*(e0x*vy[0] - e0y*vx[0]);
    const float a1 = N*e1y, b1 = -N*e1x, c1 = N*(e1x*vy[1] - e1y*vx[1]);
    const float a2 = N*e2y, b2 = -N*e2x, c2 = N*(e2x*vy[2] - e2y*vx[2]);

    float mnx = fminf(fminf(vx[0],vx[1]),vx[2]);
    float mxx = fmaxf(fmaxf(vx[0],vx[1]),vx[2]);
    float mny = fminf(fminf(vy[0],vy[1]),vy[2]);
    float mxy = fmaxf(fmaxf(vy[0],vy[1]),vy[2]);
    mnx = fmaxf(fminf(mnx, 1e6f), -1e6f);  mxx = fmaxf(fminf(mxx, 1e6f), -1e6f);
    mny = fmaxf(fminf(mny, 1e6f), -1e6f);  mxy = fmaxf(fminf(mxy, 1e6f), -1e6f);
    const int bx0 = max(0,     (int)floorf(mnx) - 1);
    const int bx1 = min(RES-1, (int)ceilf (mxx) + 1);
    const int by0 = max(0,     (int)floorf(mny) - 1);
    const int by1 = min(RES-1, (int)ceilf (mxy) + 1);
    const bool empty = (bx0 > bx1) || (by0 > by1);

    // ---- per-row analytic max ----
    float rowmax = 0.0f;
    if (!empty && threadIdx.x <= (unsigned)(by1 - by0)) {
        const float fy = (float)(by0 + (int)threadIdx.x);
        const float B0 = fmaf(b0, fy, c0);
        const float B1 = fmaf(b1, fy, c1);
        const float B2 = fmaf(b2, fy, c2);

        const float l0 = 1.0f / (fabsf(a0) + fabsf(B0) + 1e-30f);
        const float l1 = 1.0f / (fabsf(a1) + fabsf(B1) + 1e-30f);
        const float l2 = 1.0f / (fabsf(a2) + fabsf(B2) + 1e-30f);
        const float n0 = a0*l0, p0 = B0*l0;
        const float n1 = a1*l1, p1 = B1*l1;
        const float n2 = a2*l2, p2 = B2*l2;
        const float qa = 3.0f * n0*n1*n2;
        const float qb = 2.0f * (n0*n1*p2 + n0*n2*p1 + n1*n2*p0);
        const float qc = n0*p1*p2 + n1*p0*p2 + n2*p0*p1;

        float x1, x2;
        if (fabsf(qa) > 1e-30f) {
            const float disc = qb*qb - 4.0f*qa*qc;
            if (disc >= 0.0f) {
                const float rt = sqrtf(disc);
                x1 = (-qb - rt) / (2.0f*qa);
                x2 = (-qb + rt) / (2.0f*qa);
            } else {
                x1 = x2 = -qb / (2.0f*qa);
            }
        } else if (fabsf(qb) > 1e-30f) {
            x1 = x2 = -qc / qb;
        } else {
            x1 = x2 = (float)bx0;
        }

        const int f1 = (int)floorf(x1), f2 = (int)floorf(x2);
        int cand[12] = { f1-1, f1, f1+1, f1+2,  f2-1, f2, f2+1, f2+2,
                         bx0, bx0+1, bx1-1, bx1 };
#pragma unroll
        for (int k = 0; k < 12; ++k) {
            const int xi = min(max(cand[k], bx0), bx1);
            const float fx = (float)xi;
            const float u1 = fmaxf(fmaf(a0, fx, B0), 0.0f);
            const float u2 = fmaxf(fmaf(a1, fx, B1), 0.0f);
            const float u3 = fmaxf(fmaf(a2, fx, B2), 0.0f);
            rowmax = fmaxf(rowmax, u1*u2*u3);
        }
    }

#pragma unroll
    for (int off = 32; off > 0; off >>= 1)
        rowmax = fmaxf(rowmax, __shfl_down(rowmax, off, 64));
    __shared__ float smx[4];
    __shared__ float scorner[4];
    const int lane = threadIdx.x & 63, wv = threadIdx.x >> 6;
    if (lane == 0) smx[wv] = rowmax;

    if (threadIdx.x < 4) {
        const float fx = (threadIdx.x & 1) ? 255.0f : 0.0f;
        const float fy = (threadIdx.x & 2) ? 255.0f : 0.0f;
        const float u1 = fmaxf(fmaf(a0, fx, fmaf(b0, fy, c0)), 0.0f);
        const float u2 = fmaxf(fmaf(a1, fx, fmaf(b1, fy, c1)), 0.0f);
        const float u3 = fmaxf(fmaf(a2, fx, fmaf(b2, fy, c2)), 0.0f);
        scorner[threadIdx.x] = u1*u2*u3;
    }
    __syncthreads();

    if (threadIdx.x == 0) {
        const float mn = fminf(fminf(scorner[0], scorner[1]),
                               fminf(scorner[2], scorner[3]));
        float mx = fmaxf(fmaxf(smx[0], smx[1]), fmaxf(smx[2], smx[3]));
        mx = fmaxf(mx, mn);
        const float ik = LOG2E2 / (mx - mn + EPSF);
        float* r = coef + ((size_t)b * NTRI + t) * CPT;
        r[0]=a0; r[1]=b0; r[2]=c0; r[3]=a1; r[4]=b1; r[5]=c1;
        r[6]=a2; r[7]=b2; r[8]=c2;
        r[9]=ik; r[10]=mn*ik; r[11]=0.0f;
        bbox[(size_t)b * NTRI + t] = empty ? 0x00FF00FFu
            : ((unsigned)bx0 | ((unsigned)bx1 << 8) |
               ((unsigned)by0 << 16) | ((unsigned)by1 << 24));
    }
}

// ---------------------------------------------------------------------------
// Kernel B: ONE block per (batch, 16x16 tile) = 512 blocks. All 1000 tris
// culled by this block (4 ballot groups, wave-local bases via readfirstlane);
// survivors compacted to a u16 list, staged to LDS in <=CAPC-record passes,
// then a uniform-broadcast eval walk. Each pixel has a single owner block ->
// plain store, no atomics, no output pre-zeroing anywhere.
// ---------------------------------------------------------------------------
__global__ __launch_bounds__(256) void rasterize(
    const float* __restrict__ coef, const unsigned int* __restrict__ bbox,
    float* __restrict__ out)
{
    __shared__ float cl[CAPC * CPT];          // 15 KB
    __shared__ unsigned short s_list[1024];
    __shared__ int s_n;

    const int blk  = blockIdx.x;
    const int b    = blk >> 8;
    const int tile = blk & 255;               // 16x16 tiles of 16x16 px
    const int tx0  = (tile >> 4) << 4;
    const int ty0  = (tile & 15) << 4;

    const int l  = threadIdx.x & 63;
    const int tid = threadIdx.x;

    if (tid == 0) s_n = 0;
    __syncthreads();

    // cull all 1000 tris in 4 groups of 250
    const unsigned int* bbp = bbox + (size_t)b * NTRI;
#pragma unroll
    for (int g = 0; g < 4; ++g) {
        const int idx = g * 250 + tid;        // tid 250..255 -> no tri
        bool hit = false;
        if (tid < 250) {
            const unsigned int w = bbp[idx];
            const int tbx0 = w & 255, tbx1 = (w >> 8) & 255;
            const int tby0 = (w >> 16) & 255, tby1 = w >> 24;
            hit = !(tbx1 < tx0 || tbx0 > tx0 + 15 || tby1 < ty0 || tby0 > ty0 + 15);
        }
        const unsigned long long m = __ballot(hit);
        int base = 0;
        if (l == 0) base = atomicAdd(&s_n, (int)__popcll(m));
        base = __builtin_amdgcn_readfirstlane(base);
        if (hit) {
            const int pos = base + (int)__popcll(m & ((1ull << l) - 1ull));
            s_list[pos] = (unsigned short)idx;
        }
    }
    __syncthreads();
    const int n = s_n;

    const int px = tx0 + (tid >> 4);
    const int py = ty0 + (tid & 15);
    const float fx = (float)px, fy = (float)py;
    const float* cb = coef + (size_t)b * NTRI * CPT;

    float acc = 0.0f;
    for (int start = 0; start < n; start += CAPC) {
        const int cnt = min(CAPC, n - start);
        // stage this pass's survivor records
        for (int j = tid; j < cnt * CPT; j += 256) {
            const int k = j / CPT, w = j - k * CPT;
            cl[j] = cb[(int)s_list[start + k] * CPT + w];
        }
        __syncthreads();
#pragma unroll 2
        for (int k = 0; k < cnt; ++k) {
            const float* r = &cl[k * CPT];
            const float u1 = fmaxf(fmaf(r[0], fx, fmaf(r[1], fy, r[2])), 0.0f);
            const float u2 = fmaxf(fmaf(r[3], fx, fmaf(r[4], fy, r[5])), 0.0f);
            const float u3 = fmaxf(fmaf(r[6], fx, fmaf(r[7], fy, r[8])), 0.0f);
            const float e  = __builtin_amdgcn_exp2f(fmaf(u1*u2*u3, r[9], -r[10]));
            acc += __builtin_amdgcn_rcpf(1.0f + e);
        }
        __syncthreads();
    }

    out[(size_t)b * NPIX + (size_t)px * RES + py] = fmaf(-2.0f, acc, (float)n);
}

extern "C" void kernel_launch(void* const* d_in, const int* in_sizes, int n_in,
                              void* d_out, int out_size, void* d_ws, size_t ws_size,
                              hipStream_t stream)
{
    const float* meshes = (const float*)d_in[0];
    const float* Km     = (const float*)d_in[1];
    const int*   midx   = (const int*)d_in[2];
    const float* cams   = (const float*)d_in[3];
    float* out = (float*)d_out;

    const int batch = in_sizes[3] / 12;     // camera_poses is (B,3,4)

    float* coef = (float*)d_ws;                               // batch*1000*12 f32
    unsigned int* bbox =
        (unsigned int*)((char*)d_ws + (size_t)batch * NTRI * CPT * sizeof(float));

    tri_setup<<<dim3(batch * NTRI), dim3(256), 0, stream>>>(
        meshes, Km, midx, cams, coef, bbox);
    rasterize<<<dim3(batch * 256), dim3(256), 0, stream>>>(coef, bbox, out);
}

// Round 15
// 90.495 us; speedup vs baseline: 1.3167x; 1.3167x over previous
//
#include <hip/hip_runtime.h>

#define RES    256
#define NPIX   (RES * RES)
#define NTRI   1000
#define EPSF   1e-8f
#define CPT    12            // coef dwords per triangle
#define CAPL   1024          // list capacity (u16) per tile
#define SLICE  32            // survivors per work item
#define LOG2E2 2.8853900817779268f   // 2*log2(e)

// coef (12 f32/tri): a0,b0,c0,a1,b1,c1,a2,b2,c2, ik, mn, pad
//   edge_i(px,py)=a*px+b*py+c ; x2=(s-mn)*ik ; tanh = 1 - 2*rcp(1+exp2(x2))
// bbox (1 u32/tri): bx0 | bx1<<8 | by0<<16 | by1<<24 ; empty = 0x00FF00FF
// Per-tile u16 survivor lists (exclusive 2KB regions); work items =
// (gtile<<6 | slice), each covering <=32 survivors -> balanced eval.
// Exactness: mn>0 only for fullgrid-bbox tris (in every tile list); culled
// tris contribute tanh(0)=0 exactly; survivor-but-outside px: (0-0)*ik -> 0.5
// and cnt-2*0.5 = 0 exactly (same fmaf tree everywhere).

// ---------------------------------------------------------------------------
// Kernel A: one block per (batch, triangle). Thread = one bbox row (analytic
// min/max: corners for mn, per-row quadratic-root candidates for mx).
// Also zeroes out image and the two counters.
// ---------------------------------------------------------------------------
__global__ __launch_bounds__(256) void tri_setup(
    const float* __restrict__ meshes, const float* __restrict__ Km,
    const int* __restrict__ midx, const float* __restrict__ cams,
    float* __restrict__ coef, unsigned int* __restrict__ bbox,
    float* __restrict__ out, int nout, int* __restrict__ nitems,
    int* __restrict__ pad_unused)
{
    const int blk = blockIdx.x;
    const int b = blk / NTRI;
    const int t = blk - b * NTRI;

    { const int g = blk * 256 + threadIdx.x; if (g < nout) out[g] = 0.0f; }
    if (blk == 0 && threadIdx.x == 0) nitems[0] = 0;

    const float* cam = cams + b * 12;
    float M[12];
#pragma unroll
    for (int i = 0; i < 3; ++i) {
        const float k0 = Km[i*3+0], k1 = Km[i*3+1], k2 = Km[i*3+2];
#pragma unroll
        for (int j = 0; j < 4; ++j)
            M[i*4+j] = k0*cam[j] + k1*cam[4+j] + k2*cam[8+j];
    }
    const int m = midx[b];
    const float* tv = meshes + ((size_t)m * NTRI + t) * 9;
    float vx[3], vy[3];
#pragma unroll
    for (int v = 0; v < 3; ++v) {
        const float X = tv[v*3+0], Y = tv[v*3+1], Z = tv[v*3+2];
        const float w = M[8]*X + M[9]*Y + M[10]*Z + M[11] + EPSF;
        vx[v] = (M[0]*X + M[1]*Y + M[2]*Z + M[3]) / w;
        vy[v] = (M[4]*X + M[5]*Y + M[6]*Z + M[7]) / w;
    }

    const float e0x = vx[1]-vx[0], e0y = vy[1]-vy[0];
    const float e1x = vx[2]-vx[1], e1y = vy[2]-vy[1];
    const float e2x = vx[0]-vx[2], e2y = vy[0]-vy[2];
    const float N = e0x*e2y - e0y*e2x + EPSF;

    const float a0 = N*e0y, b0 = -N*e0x, c0 = N*(e0x*vy[0] - e0y*vx[0]);
    const float a1 = N*e1y, b1 = -N*e1x, c1 = N*(e1x*vy[1] - e1y*vx[1]);
    const float a2 = N*e2y, b2 = -N*e2x, c2 = N*(e2x*vy[2] - e2y*vx[2]);

    float mnx = fminf(fminf(vx[0],vx[1]),vx[2]);
    float mxx = fmaxf(fmaxf(vx[0],vx[1]),vx[2]);
    float mny = fminf(fminf(vy[0],vy[1]),vy[2]);
    float mxy = fmaxf(fmaxf(vy[0],vy[1]),vy[2]);
    mnx = fmaxf(fminf(mnx, 1e6f), -1e6f);  mxx = fmaxf(fminf(mxx, 1e6f), -1e6f);
    mny = fmaxf(fminf(mny, 1e6f), -1e6f);  mxy = fmaxf(fminf(mxy, 1e6f), -1e6f);
    const int bx0 = max(0,     (int)floorf(mnx) - 1);
    const int bx1 = min(RES-1, (int)ceilf (mxx) + 1);
    const int by0 = max(0,     (int)floorf(mny) - 1);
    const int by1 = min(RES-1, (int)ceilf (mxy) + 1);
    const bool empty = (bx0 > bx1) || (by0 > by1);

    float rowmax = 0.0f;
    if (!empty && threadIdx.x <= (unsigned)(by1 - by0)) {
        const float fy = (float)(by0 + (int)threadIdx.x);
        const float B0 = fmaf(b0, fy, c0);
        const float B1 = fmaf(b1, fy, c1);
        const float B2 = fmaf(b2, fy, c2);

        const float l0 = 1.0f / (fabsf(a0) + fabsf(B0) + 1e-30f);
        const float l1 = 1.0f / (fabsf(a1) + fabsf(B1) + 1e-30f);
        const float l2 = 1.0f / (fabsf(a2) + fabsf(B2) + 1e-30f);
        const float n0 = a0*l0, p0 = B0*l0;
        const float n1 = a1*l1, p1 = B1*l1;
        const float n2 = a2*l2, p2 = B2*l2;
        const float qa = 3.0f * n0*n1*n2;
        const float qb = 2.0f * (n0*n1*p2 + n0*n2*p1 + n1*n2*p0);
        const float qc = n0*p1*p2 + n1*p0*p2 + n2*p0*p1;

        float x1, x2;
        if (fabsf(qa) > 1e-30f) {
            const float disc = qb*qb - 4.0f*qa*qc;
            if (disc >= 0.0f) {
                const float rt = sqrtf(disc);
                x1 = (-qb - rt) / (2.0f*qa);
                x2 = (-qb + rt) / (2.0f*qa);
            } else {
                x1 = x2 = -qb / (2.0f*qa);
            }
        } else if (fabsf(qb) > 1e-30f) {
            x1 = x2 = -qc / qb;
        } else {
            x1 = x2 = (float)bx0;
        }

        const int f1 = (int)floorf(x1), f2 = (int)floorf(x2);
        int cand[12] = { f1-1, f1, f1+1, f1+2,  f2-1, f2, f2+1, f2+2,
                         bx0, bx0+1, bx1-1, bx1 };
#pragma unroll
        for (int k = 0; k < 12; ++k) {
            const int xi = min(max(cand[k], bx0), bx1);
            const float fx = (float)xi;
            const float u1 = fmaxf(fmaf(a0, fx, B0), 0.0f);
            const float u2 = fmaxf(fmaf(a1, fx, B1), 0.0f);
            const float u3 = fmaxf(fmaf(a2, fx, B2), 0.0f);
            rowmax = fmaxf(rowmax, u1*u2*u3);
        }
    }

#pragma unroll
    for (int off = 32; off > 0; off >>= 1)
        rowmax = fmaxf(rowmax, __shfl_down(rowmax, off, 64));
    __shared__ float smx[4];
    __shared__ float scorner[4];
    const int lane = threadIdx.x & 63, wv = threadIdx.x >> 6;
    if (lane == 0) smx[wv] = rowmax;

    if (threadIdx.x < 4) {
        const float fx = (threadIdx.x & 1) ? 255.0f : 0.0f;
        const float fy = (threadIdx.x & 2) ? 255.0f : 0.0f;
        const float u1 = fmaxf(fmaf(a0, fx, fmaf(b0, fy, c0)), 0.0f);
        const float u2 = fmaxf(fmaf(a1, fx, fmaf(b1, fy, c1)), 0.0f);
        const float u3 = fmaxf(fmaf(a2, fx, fmaf(b2, fy, c2)), 0.0f);
        scorner[threadIdx.x] = u1*u2*u3;
    }
    __syncthreads();

    if (threadIdx.x == 0) {
        const float mn = fminf(fminf(scorner[0], scorner[1]),
                               fminf(scorner[2], scorner[3]));
        float mx = fmaxf(fmaxf(smx[0], smx[1]), fmaxf(smx[2], smx[3]));
        mx = fmaxf(mx, mn);
        const float ik = LOG2E2 / (mx - mn + EPSF);
        float* r = coef + ((size_t)b * NTRI + t) * CPT;
        r[0]=a0; r[1]=b0; r[2]=c0; r[3]=a1; r[4]=b1; r[5]=c1;
        r[6]=a2; r[7]=b2; r[8]=c2;
        r[9]=ik; r[10]=mn; r[11]=0.0f;
        bbox[(size_t)b * NTRI + t] = empty ? 0x00FF00FFu
            : ((unsigned)bx0 | ((unsigned)bx1 << 8) |
               ((unsigned)by0 << 16) | ((unsigned)by1 << 24));
    }
}

// ---------------------------------------------------------------------------
// Kernel B: cull. Block = (batch, 16x16 tile). Ballot-compact the tile's
// survivors to LDS, write the u16 list to an exclusive 2KB region (coalesced),
// emit ceil(n/32) work items via one global atomicAdd.
// ---------------------------------------------------------------------------
__global__ __launch_bounds__(256) void cull(
    const unsigned int* __restrict__ bbox, int* __restrict__ cnt,
    unsigned short* __restrict__ lists, unsigned int* __restrict__ items,
    int* __restrict__ nitems)
{
    __shared__ unsigned short s_list[CAPL];
    __shared__ int s_n;

    const int gtile = blockIdx.x;
    const int b    = gtile >> 8;
    const int t256 = gtile & 255;
    const int tx0  = (t256 >> 4) << 4;
    const int ty0  = (t256 & 15) << 4;

    const int tid = threadIdx.x;
    const int l   = tid & 63;

    if (tid == 0) s_n = 0;
    __syncthreads();

    const unsigned int* bbp = bbox + (size_t)b * NTRI;
#pragma unroll
    for (int g = 0; g < 4; ++g) {
        const int idx = g * 250 + tid;
        bool hit = false;
        if (tid < 250) {
            const unsigned int w = bbp[idx];
            const int tbx0 = w & 255, tbx1 = (w >> 8) & 255;
            const int tby0 = (w >> 16) & 255, tby1 = w >> 24;
            hit = !(tbx1 < tx0 || tbx0 > tx0 + 15 || tby1 < ty0 || tby0 > ty0 + 15);
        }
        const unsigned long long m = __ballot(hit);
        int base = 0;
        if (l == 0) base = atomicAdd(&s_n, (int)__popcll(m));
        base = __builtin_amdgcn_readfirstlane(base);
        if (hit) {
            const int pos = base + (int)__popcll(m & ((1ull << l) - 1ull));
            s_list[pos] = (unsigned short)idx;
        }
    }
    __syncthreads();
    const int n = s_n;

    unsigned short* gl = lists + (size_t)gtile * CAPL;
    for (int j = tid; j < n; j += 256) gl[j] = s_list[j];

    if (tid == 0) {
        cnt[gtile] = n;
        const int ni = (n + SLICE - 1) / SLICE;
        if (ni > 0) {
            const int pos = atomicAdd(nitems, ni);
            for (int s = 0; s < ni; ++s)
                items[pos + s] = ((unsigned)gtile << 6) | (unsigned)s;
        }
    }
}

// ---------------------------------------------------------------------------
// Kernel C: eval. Grid-strided over work items (uniform 32-survivor slices ->
// balanced, no scheduling atomics). Stage slice records to LDS, 256 px eval,
// atomicAdd into pre-zeroed out.
// ---------------------------------------------------------------------------
__global__ __launch_bounds__(256) void eval(
    const float* __restrict__ coef, const int* __restrict__ cnt,
    const unsigned short* __restrict__ lists,
    const unsigned int* __restrict__ items, const int* __restrict__ nitems,
    float* __restrict__ out)
{
    __shared__ float cl[SLICE * CPT];   // 1.5 KB

    const int NI  = nitems[0];
    const int tid = threadIdx.x;

    for (int it = blockIdx.x; it < NI; it += gridDim.x) {
        const unsigned int w = items[it];
        const int slice = (int)(w & 63u);
        const int gtile = (int)(w >> 6);
        const int b    = gtile >> 8;
        const int t256 = gtile & 255;
        const int tx0  = (t256 >> 4) << 4;
        const int ty0  = (t256 & 15) << 4;

        const int n     = cnt[gtile];
        const int start = slice * SLICE;
        const int cs    = min(SLICE, n - start);

        const unsigned short* lp = lists + (size_t)gtile * CAPL + start;
        const float* cb = coef + (size_t)b * NTRI * CPT;
        for (int j = tid; j < cs * CPT; j += 256) {
            const int k = j / CPT, o = j - k * CPT;
            cl[j] = cb[(int)lp[k] * CPT + o];
        }
        __syncthreads();

        const int px = tx0 + (tid >> 4);
        const int py = ty0 + (tid & 15);
        const float fx = (float)px, fy = (float)py;

        float acc = 0.0f;
#pragma unroll 2
        for (int k = 0; k < cs; ++k) {
            const float* r = &cl[k * CPT];
            const float u1 = fmaxf(fmaf(r[0], fx, fmaf(r[1], fy, r[2])), 0.0f);
            const float u2 = fmaxf(fmaf(r[3], fx, fmaf(r[4], fy, r[5])), 0.0f);
            const float u3 = fmaxf(fmaf(r[6], fx, fmaf(r[7], fy, r[8])), 0.0f);
            const float e  = __builtin_amdgcn_exp2f((u1*u2*u3 - r[10]) * r[9]);
            acc += __builtin_amdgcn_rcpf(1.0f + e);
        }

        atomicAdd(out + (size_t)b * NPIX + (size_t)px * RES + py,
                  fmaf(-2.0f, acc, (float)cs));
        __syncthreads();
    }
}

extern "C" void kernel_launch(void* const* d_in, const int* in_sizes, int n_in,
                              void* d_out, int out_size, void* d_ws, size_t ws_size,
                              hipStream_t stream)
{
    const float* meshes = (const float*)d_in[0];
    const float* Km     = (const float*)d_in[1];
    const int*   midx   = (const int*)d_in[2];
    const float* cams   = (const float*)d_in[3];
    float* out = (float*)d_out;

    const int batch = in_sizes[3] / 12;     // camera_poses is (B,3,4)
    const int ntile = batch * 256;

    // ws layout
    char* p = (char*)d_ws;
    float* coef = (float*)p;                 p += (size_t)batch * NTRI * CPT * 4;
    unsigned int* bbox = (unsigned int*)p;   p += (size_t)batch * NTRI * 4;
    int* cnt = (int*)p;                      p += (size_t)ntile * 4;
    int* nitems = (int*)p;                   p += 64;            // padded
    unsigned int* items = (unsigned int*)p;  p += (size_t)ntile * 32 * 4;
    unsigned short* lists = (unsigned short*)p;

    tri_setup<<<dim3(batch * NTRI), dim3(256), 0, stream>>>(
        meshes, Km, midx, cams, coef, bbox, out, batch * NPIX, nitems, cnt);
    cull<<<dim3(ntile), dim3(256), 0, stream>>>(bbox, cnt, lists, items, nitems);
    eval<<<dim3(2048), dim3(256), 0, stream>>>(coef, cnt, lists, items, nitems, out);
}